// Round 1
// baseline (204.396 us; speedup 1.0000x reference)
//
#include <hip/hip_runtime.h>

#define HH   56
#define WW   56
#define HWP  (HH * WW)     // 3136
#define CC   256
#define GG   16
#define CGR  16            // channels per group
#define KT   7
#define KK   49
#define KKG  784
#define RC   64
#define TH   2             // rows per involution block

// ---------------- tiled GEMM: Y[b][m][p] = sum_k W[m][k] * X[b][k][p] + bias[m] ----
// grid: (HWP/NT, ceil(M/MT), B), block 256
template<int MT, int NT, int TM, int TN, int KC, int PAD>
__global__ __launch_bounds__(256)
void gemm_wx(const float* __restrict__ Wm, const float* __restrict__ bias,
             const float* __restrict__ X, float* __restrict__ Y,
             int M, int Kd)
{
    const int b  = blockIdx.z;
    const int bm = blockIdx.y * MT;
    const int bn = blockIdx.x * NT;
    const float* Xb = X + b * Kd * HWP;
    float*       Yb = Y + b * M  * HWP;

    __shared__ __align__(16) float sW[KC][MT + PAD];  // transposed W tile
    __shared__ __align__(16) float sX[KC][NT];

    const int t  = threadIdx.x;
    const int tn = t % (NT / TN);
    const int tm = t / (NT / TN);

    float acc[TM][TN];
#pragma unroll
    for (int i = 0; i < TM; ++i)
#pragma unroll
        for (int j = 0; j < TN; ++j) acc[i][j] = 0.f;

    for (int kc = 0; kc < Kd; kc += KC) {
        // stage W chunk (MT x KC), transposed: sW[c][m]
        for (int i = t; i < MT * KC; i += 256) {
            const int c = i % KC, m = i / KC;
            const int mg = bm + m;
            float v = 0.f;
            if (mg < M) v = Wm[mg * Kd + kc + c];
            sW[c][m] = v;
        }
        // stage X chunk (KC x NT)
        for (int i = t; i < KC * NT; i += 256) {
            const int n = i % NT, c = i / NT;
            sX[c][n] = Xb[(kc + c) * HWP + bn + n];
        }
        __syncthreads();
#pragma unroll
        for (int c = 0; c < KC; ++c) {
            float wv[TM], xv[TN];
#pragma unroll
            for (int i = 0; i < TM; i += 4)
                *(float4*)&wv[i] = *(const float4*)&sW[c][tm * TM + i];
#pragma unroll
            for (int j = 0; j < TN; j += 4)
                *(float4*)&xv[j] = *(const float4*)&sX[c][tn * TN + j];
#pragma unroll
            for (int i = 0; i < TM; ++i)
#pragma unroll
                for (int j = 0; j < TN; ++j)
                    acc[i][j] += wv[i] * xv[j];
        }
        __syncthreads();
    }
#pragma unroll
    for (int i = 0; i < TM; ++i) {
        const int m = bm + tm * TM + i;
        if (m < M) {
            const float bv = bias[m];
            float4 v;
            v.x = acc[i][0] + bv; v.y = acc[i][1] + bv;
            v.z = acc[i][2] + bv; v.w = acc[i][3] + bv;
            *(float4*)&Yb[m * HWP + bn + tn * TN] = v;
        }
    }
}

// ---------------- involution: out[b][g*16+c][h][w] = sum_{kh,kw} kern[b][g*49+kh*7+kw][h][w]
//                               * x[b][g*16+c][h+kh-3][w+kw-3]  (zero padded)
// grid: (HH/TH, GG, B), block 256
__global__ __launch_bounds__(256)
void invol(const float* __restrict__ x, const float* __restrict__ kern,
           float* __restrict__ out)
{
    const int h0 = blockIdx.x * TH;
    const int g  = blockIdx.y;
    const int b  = blockIdx.z;

    __shared__ __align__(16) float sK[KK][TH][WW];        // 49*2*56*4  = 21.9 KB
    __shared__ __align__(16) float sX[TH + 6][63][16];    // 8*63*16*4  = 32.25 KB
                                                          // w padded 62->63: row parity
                                                          // spreads bank groups on b128 reads
    const int t = threadIdx.x;

    // zero-fill sX (covers halo/borders)
    {
        float* p = &sX[0][0][0];
        for (int i = t; i < (TH + 6) * 63 * 16; i += 256) p[i] = 0.f;
    }
    __syncthreads();
    // stage x interior, transposed to [row][w+3][ch]
    {
        const int ch = t & 15;
        const int wq = t >> 4;   // 0..15
        const float* xb = x + (b * CC + g * CGR + ch) * HWP;
#pragma unroll
        for (int rr = 0; rr < TH + 6; ++rr) {
            const int hh = h0 - 3 + rr;
            if (hh < 0 || hh >= HH) continue;
#pragma unroll
            for (int k = 0; k < 4; ++k) {
                const int w = wq + 16 * k;
                if (w < WW) sX[rr][w + 3][ch] = xb[hh * WW + w];
            }
        }
    }
    // stage kern strip
    {
        const float* kb = kern + (b * KKG + g * KK) * HWP;
        float* p = &sK[0][0][0];
        for (int i = t; i < KK * TH * WW; i += 256) {
            const int tap = i / (TH * WW);
            const int rem = i % (TH * WW);
            p[i] = kb[tap * HWP + (h0 + rem / WW) * WW + (rem % WW)];
        }
    }
    __syncthreads();

    if (t < 224) {                 // 4 chg * 2 r * 28 wg
        const int chg = t & 3;     // channel quad
        const int r   = (t >> 2) & 1;
        const int wg  = t >> 3;    // 0..27
        const int w0  = wg * 2;
        float a00=0,a01=0,a02=0,a03=0, a10=0,a11=0,a12=0,a13=0;
#pragma unroll
        for (int kh = 0; kh < KT; ++kh) {
            const int rr = r + kh;
            float4 xv[8];
#pragma unroll
            for (int j = 0; j < 8; ++j)
                xv[j] = *(const float4*)&sX[rr][w0 + j][chg * 4];
            float2 kv[7];
#pragma unroll
            for (int kw = 0; kw < KT; ++kw)
                kv[kw] = *(const float2*)&sK[kh * KT + kw][r][w0];
#pragma unroll
            for (int kw = 0; kw < KT; ++kw) {
                const float k0 = kv[kw].x, k1 = kv[kw].y;
                const float4 xa = xv[kw], xc = xv[kw + 1];
                a00 += k0 * xa.x; a01 += k0 * xa.y; a02 += k0 * xa.z; a03 += k0 * xa.w;
                a10 += k1 * xc.x; a11 += k1 * xc.y; a12 += k1 * xc.z; a13 += k1 * xc.w;
            }
        }
        const int cbase = b * CC + g * CGR + chg * 4;
        const int poff  = (h0 + r) * WW + w0;
        *(float2*)&out[(cbase + 0) * HWP + poff] = make_float2(a00, a10);
        *(float2*)&out[(cbase + 1) * HWP + poff] = make_float2(a01, a11);
        *(float2*)&out[(cbase + 2) * HWP + poff] = make_float2(a02, a12);
        *(float2*)&out[(cbase + 3) * HWP + poff] = make_float2(a03, a13);
    }
}

extern "C" void kernel_launch(void* const* d_in, const int* in_sizes, int n_in,
                              void* d_out, int out_size, void* d_ws, size_t ws_size,
                              hipStream_t stream)
{
    const float* x  = (const float*)d_in[0];   // (4,256,56,56)
    const float* rw = (const float*)d_in[1];   // (64,256)
    const float* rb = (const float*)d_in[2];   // (64,)
    const float* sw = (const float*)d_in[3];   // (784,64)
    const float* sb = (const float*)d_in[4];   // (784,)
    float* out  = (float*)d_out;               // (4,256,56,56)

    float* hbuf = (float*)d_ws;                // (4,64,3136)  = 3.2 MB
    float* kbuf = hbuf + 4 * RC * HWP;         // (4,784,3136) = 39.3 MB

    // h = reduce_w @ x + reduce_b
    gemm_wx<64, 64, 4, 4, 32, 4><<<dim3(HWP / 64, 1, 4), 256, 0, stream>>>(
        rw, rb, x, hbuf, RC, CC);
    // kern = span_w @ h + span_b
    gemm_wx<128, 64, 8, 4, 32, 4><<<dim3(HWP / 64, (KKG + 127) / 128, 4), 256, 0, stream>>>(
        sw, sb, hbuf, kbuf, KKG, RC);
    // grouped dynamic 7x7 multiply-reduce
    invol<<<dim3(HH / TH, GG, 4), 256, 0, stream>>>(x, kbuf, out);
}

// Round 2
// 197.796 us; speedup vs baseline: 1.0334x; 1.0334x over previous
//
#include <hip/hip_runtime.h>

#define HH   56
#define WW   56
#define HWP  (HH * WW)     // 3136
#define CC   256
#define GG   16
#define CGR  16            // channels per group
#define KT   7
#define KK   49
#define KKG  784
#define RC   64
#define TH   2             // rows per involution block

// ---------------- tiled GEMM: Y[b][m][p] = sum_k W[m][k] * X[b][k][p] + bias[m] ----
template<int MT, int NT, int TM, int TN, int KC, int PAD>
__global__ __launch_bounds__(256)
void gemm_wx(const float* __restrict__ Wm, const float* __restrict__ bias,
             const float* __restrict__ X, float* __restrict__ Y,
             int M, int Kd)
{
    const int b  = blockIdx.z;
    const int bm = blockIdx.y * MT;
    const int bn = blockIdx.x * NT;
    const float* Xb = X + b * Kd * HWP;
    float*       Yb = Y + b * M  * HWP;

    __shared__ __align__(16) float sW[KC][MT + PAD];  // transposed W tile
    __shared__ __align__(16) float sX[KC][NT];

    const int t  = threadIdx.x;
    const int tn = t % (NT / TN);
    const int tm = t / (NT / TN);

    float acc[TM][TN];
#pragma unroll
    for (int i = 0; i < TM; ++i)
#pragma unroll
        for (int j = 0; j < TN; ++j) acc[i][j] = 0.f;

    for (int kc = 0; kc < Kd; kc += KC) {
        for (int i = t; i < MT * KC; i += 256) {
            const int c = i % KC, m = i / KC;
            const int mg = bm + m;
            float v = 0.f;
            if (mg < M) v = Wm[mg * Kd + kc + c];
            sW[c][m] = v;
        }
        for (int i = t; i < KC * NT; i += 256) {
            const int n = i % NT, c = i / NT;
            sX[c][n] = Xb[(kc + c) * HWP + bn + n];
        }
        __syncthreads();
#pragma unroll
        for (int c = 0; c < KC; ++c) {
            float wv[TM], xv[TN];
#pragma unroll
            for (int i = 0; i < TM; i += 4)
                *(float4*)&wv[i] = *(const float4*)&sW[c][tm * TM + i];
            if constexpr (TN >= 4) {
#pragma unroll
                for (int j = 0; j < TN; j += 4)
                    *(float4*)&xv[j] = *(const float4*)&sX[c][tn * TN + j];
            } else {
                *(float2*)&xv[0] = *(const float2*)&sX[c][tn * TN];
            }
#pragma unroll
            for (int i = 0; i < TM; ++i)
#pragma unroll
                for (int j = 0; j < TN; ++j)
                    acc[i][j] += wv[i] * xv[j];
        }
        __syncthreads();
    }
#pragma unroll
    for (int i = 0; i < TM; ++i) {
        const int m = bm + tm * TM + i;
        if (m < M) {
            const float bv = bias[m];
            if constexpr (TN >= 4) {
                float4 v;
                v.x = acc[i][0] + bv; v.y = acc[i][1] + bv;
                v.z = acc[i][2] + bv; v.w = acc[i][3] + bv;
                *(float4*)&Yb[m * HWP + bn + tn * TN] = v;
            } else {
                float2 v;
                v.x = acc[i][0] + bv; v.y = acc[i][1] + bv;
                *(float2*)&Yb[m * HWP + bn + tn * TN] = v;
            }
        }
    }
}

// ---------------- fused kern-gen + involution -------------------------------
// Per block (b, g, 2-row strip):
//   phase B2: kern[g*49+tap][strip] = span_w[g*49+tap][:] . h[:][strip] + span_b
//             computed straight into LDS (no HBM round trip).
//             lane->pixel (coalesced h loads), tap-half per wave (uniform ->
//             span_w rows come in as s_load / SGPR operands of v_fmac).
//   phase C : out[b][g*16+c][h][w] = sum_{kh,kw} sK[kh*7+kw][h][w]
//             * x[b][g*16+c][h+kh-3][w+kw-3]
__global__ __launch_bounds__(256)
void invol_fused(const float* __restrict__ x, const float* __restrict__ h,
                 const float* __restrict__ sw, const float* __restrict__ sb,
                 float* __restrict__ out)
{
    const int h0 = blockIdx.x * TH;
    const int g  = blockIdx.y;
    const int b  = blockIdx.z;

    __shared__ __align__(16) float sK[KK][TH][WW];        // 21.9 KB
    __shared__ __align__(16) float sX[TH + 6][63][16];    // 32.25 KB  (54.2 KB total -> 2 blocks/CU)

    const int t = threadIdx.x;

    // zero-fill sX (halo/borders)
    {
        float* p = &sX[0][0][0];
        for (int i = t; i < (TH + 6) * 63 * 16; i += 256) p[i] = 0.f;
    }
    __syncthreads();

    // stage x interior, transposed to [row][w+3][ch]
    {
        const int ch = t & 15;
        const int wq = t >> 4;
        const float* xb = x + (size_t)(b * CC + g * CGR + ch) * HWP;
#pragma unroll
        for (int rr = 0; rr < TH + 6; ++rr) {
            const int hh = h0 - 3 + rr;
            if (hh < 0 || hh >= HH) continue;
#pragma unroll
            for (int k = 0; k < 4; ++k) {
                const int w = wq + 16 * k;
                if (w < WW) sX[rr][w + 3][ch] = xb[hh * WW + w];
            }
        }
    }

    // kern-gen into sK
    {
        const int wave = t >> 6;
        const int half = __builtin_amdgcn_readfirstlane(wave >> 1);  // 0/1, wave-uniform
        const int px   = (t & 63) + 64 * (wave & 1);                 // 0..127
        if (px < TH * WW) {
            const float* hb = h + (size_t)b * RC * HWP + h0 * WW + px;
            float hreg[RC];
#pragma unroll
            for (int c = 0; c < RC; ++c) hreg[c] = hb[c * HWP];      // coalesced, L2-hot
            const int tbase = half * 24;                             // taps 0..24 / 24..48
#pragma unroll
            for (int j = 0; j < 25; ++j) {
                const int tap = tbase + j;
                const float* swr = sw + (size_t)(g * KK + tap) * RC; // wave-uniform row
                float a0 = 0.f, a1 = 0.f, a2 = 0.f, a3 = 0.f;
#pragma unroll
                for (int c = 0; c < RC; c += 4) {
                    a0 += swr[c + 0] * hreg[c + 0];
                    a1 += swr[c + 1] * hreg[c + 1];
                    a2 += swr[c + 2] * hreg[c + 2];
                    a3 += swr[c + 3] * hreg[c + 3];
                }
                (&sK[tap][0][0])[px] = sb[g * KK + tap] + ((a0 + a1) + (a2 + a3));
            }
        }
    }
    __syncthreads();

    // involution
    if (t < 224) {                 // 4 chq * 2 r * 28 wg
        const int chg = t & 3;
        const int r   = (t >> 2) & 1;
        const int wg  = t >> 3;
        const int w0  = wg * 2;
        float a00=0,a01=0,a02=0,a03=0, a10=0,a11=0,a12=0,a13=0;
#pragma unroll
        for (int kh = 0; kh < KT; ++kh) {
            const int rr = r + kh;
            float4 xv[8];
#pragma unroll
            for (int j = 0; j < 8; ++j)
                xv[j] = *(const float4*)&sX[rr][w0 + j][chg * 4];
            float2 kv[7];
#pragma unroll
            for (int kw = 0; kw < KT; ++kw)
                kv[kw] = *(const float2*)&sK[kh * KT + kw][r][w0];
#pragma unroll
            for (int kw = 0; kw < KT; ++kw) {
                const float k0 = kv[kw].x, k1 = kv[kw].y;
                const float4 xa = xv[kw], xc = xv[kw + 1];
                a00 += k0 * xa.x; a01 += k0 * xa.y; a02 += k0 * xa.z; a03 += k0 * xa.w;
                a10 += k1 * xc.x; a11 += k1 * xc.y; a12 += k1 * xc.z; a13 += k1 * xc.w;
            }
        }
        const int cbase = b * CC + g * CGR + chg * 4;
        const int poff  = (h0 + r) * WW + w0;
        *(float2*)&out[(cbase + 0) * HWP + poff] = make_float2(a00, a10);
        *(float2*)&out[(cbase + 1) * HWP + poff] = make_float2(a01, a11);
        *(float2*)&out[(cbase + 2) * HWP + poff] = make_float2(a02, a12);
        *(float2*)&out[(cbase + 3) * HWP + poff] = make_float2(a03, a13);
    }
}

extern "C" void kernel_launch(void* const* d_in, const int* in_sizes, int n_in,
                              void* d_out, int out_size, void* d_ws, size_t ws_size,
                              hipStream_t stream)
{
    const float* x  = (const float*)d_in[0];   // (4,256,56,56)
    const float* rw = (const float*)d_in[1];   // (64,256)
    const float* rb = (const float*)d_in[2];   // (64,)
    const float* sw = (const float*)d_in[3];   // (784,64)
    const float* sb = (const float*)d_in[4];   // (784,)
    float* out  = (float*)d_out;               // (4,256,56,56)

    float* hbuf = (float*)d_ws;                // (4,64,3136) = 3.2 MB

    // h = reduce_w @ x + reduce_b   (392 blocks: 1.5/CU instead of 0.77/CU)
    gemm_wx<64, 32, 4, 2, 32, 4><<<dim3(HWP / 32, 1, 4), 256, 0, stream>>>(
        rw, rb, x, hbuf, RC, CC);
    // fused kern-gen + involution (kern never touches HBM)
    invol_fused<<<dim3(HH / TH, GG, 4), 256, 0, stream>>>(x, hbuf, sw, sb, out);
}